// Round 12
// baseline (6064.283 us; speedup 1.0000x reference)
//
#include <hip/hip_runtime.h>
#include <stdint.h>

// Farthest point sampling: b=16, n=65536, npoints=2048. Full-f64 decision
// pipeline (R5: harness ref is float64 ground-truth recompute; R5-R11 absmax 0).
//
// R12 = R11 (5.51 ms, model validated) + PIPELINED POLLING.
// R11's spin observes once per RT: loads are issued only after the previous
// round is consumed, so a freshly-visible store waits up to a full LLC RT
// to be seen. R12 keeps TWO rounds in flight: issue round B, then check
// round A (compiler emits s_waitcnt vmcnt(2), leaving B outstanding),
// alternate. Observation cadence ~RT/2. Self-tagged words make consuming
// either round safe at any time; torn 64-bit rounds impossible (single b64
// atomics per word).
// Everything else unchanged from R11:
//  - slots: 2 self-tagged u64 words, single-writer 64-B line
//      w0=[bd_hi32|tag|idx]  w1=[bd_lo32|tag|idx]
//  - 16 blocks x 256 thr per batch (1 wave/SIMD keeps the f64 update at
//    ~640 cy; 512-thr blocks would double it — rejected by arithmetic)
//  - wave0 polls (16 pollers/batch), waves 1-3 wait on a parity-duplexed
//    LDS mailbox; winner coords via uniform read-only P[wi] fetch
//  - parity double-buffer, unique 16-bit tags (poison 0xAAAA unmatchable),
//    skew <= 1 iteration via the rendezvous chain

#define NBATCH   16
#define NPTS     65536
#define NPOINTS  2048
#define KBLK     16                  // blocks per batch
#define THREADS  256
#define WPB      64                  // slots (waves) per batch
#define PPB      4096                // points per block
#define PPT      16                  // points per thread
#define SLOT_U64 8                   // 64-B stride: single writer per line
#define REGION_U64 (WPB * SLOT_U64)  // 4 KB per (parity,batch)

#define TAGOK(w) (((unsigned)((w) >> 16) & 0xFFFFu) == tag)

__global__ __launch_bounds__(THREADS, 1)
void fps_kernel(const float* __restrict__ pts, int* __restrict__ out,
                unsigned long long* __restrict__ slots)
{
    const int bid  = blockIdx.x;
    const int g    = bid & 15;       // batch (XCD co-location swizzle)
    const int blk  = bid >> 4;       // block within batch, 0..15
    const int tid  = threadIdx.x;
    const int lane = tid & 63;
    const int wave = tid >> 6;       // 0..3
    const int widx = (blk << 2) + wave;   // slot index within batch, 0..63

    const float* __restrict__ P = pts + (size_t)g * (NPTS * 3);

    __shared__ unsigned long long s_flag[2];   // [idx<<32 | tag], per parity

    // Register-resident coords (f32; exact when widened to f64) + f64 dist.
    float  x[PPT], y[PPT], z[PPT];
    double dist[PPT];
    const int base = blk * PPB;
#pragma unroll
    for (int j = 0; j < PPT; ++j) {
        const int idx = base + j * THREADS + tid;
        x[j] = P[idx * 3 + 0];
        y[j] = P[idx * 3 + 1];
        z[j] = P[idx * 3 + 2];
        dist[j] = 1e10;              // never survives iteration 0
    }
    if (tid == 0) { s_flag[0] = 0ull; s_flag[1] = 0ull; }
    __syncthreads();                 // once, before the loop

    double qx = (double)P[0], qy = (double)P[1], qz = (double)P[2];
    if (blk == 0 && tid == 0) out[g * NPOINTS] = 0;

    for (int it = 0; it < NPOINTS - 1; ++it) {
        // ---- f64 min-dist update + thread-local argmax (first-max) ----
        double bd = -1.0;
        int    bi = 0x7FFFFFFF;
        {
#pragma clang fp contract(off)
#pragma unroll
            for (int j = 0; j < PPT; ++j) {
                const double dx = (double)x[j] - qx;
                const double dy = (double)y[j] - qy;
                const double dz = (double)z[j] - qz;
                const double d  = (dx * dx + dy * dy) + dz * dz;
                const double nd = fmin(dist[j], d);
                dist[j] = nd;
                const bool t = nd > bd;          // strict: first-max kept
                bd = t ? nd : bd;
                bi = t ? (base + j * THREADS + tid) : bi;
            }
        }

        // ---- 64-lane butterfly argmax over (bd, bi) ----
#pragma unroll
        for (int m = 1; m < 64; m <<= 1) {
            const double od = __shfl_xor(bd, m, 64);
            const int    oi = __shfl_xor(bi, m, 64);
            const bool t = (od > bd) || (od == bd && oi < bi);
            bd = t ? od : bd; bi = t ? oi : bi;
        }

        const unsigned tag = (unsigned)(it + 1);
        const int par = it & 1;
        unsigned long long* rb =
            slots + (size_t)(par * NBATCH + g) * REGION_U64;

        // ---- publish: lanes 0..1 store the 2 self-tagged words ----
        {
            const unsigned long long B =
                (unsigned long long)__double_as_longlong(bd);
            const unsigned long long TI =
                  ((unsigned long long)tag << 16)
                | (unsigned long long)((unsigned)bi & 0xFFFFu);
            const unsigned long long hi32 =
                (lane == 0) ? (B >> 32) : (B & 0xFFFFFFFFull);
            if (lane < 2) {
                __hip_atomic_store(rb + widx * SLOT_U64 + lane,
                                   (hi32 << 32) | TI,
                                   __ATOMIC_RELAXED, __HIP_MEMORY_SCOPE_AGENT);
            }
        }

        int wi;
        if (wave == 0) {
            // ---- pipelined poll: lane i watches slot i, two rounds of
            //      loads in flight; check the older while the newer flies --
            unsigned long long* sp = rb + lane * SLOT_U64;
            __builtin_amdgcn_s_sleep(2);   // own stores can't be visible yet
            unsigned long long a0, a1, b0, b1, l0, l1;
            a0 = __hip_atomic_load(sp + 0, __ATOMIC_RELAXED,
                                   __HIP_MEMORY_SCOPE_AGENT);
            a1 = __hip_atomic_load(sp + 1, __ATOMIC_RELAXED,
                                   __HIP_MEMORY_SCOPE_AGENT);
            int guard = 0;
            for (;;) {
                b0 = __hip_atomic_load(sp + 0, __ATOMIC_RELAXED,
                                       __HIP_MEMORY_SCOPE_AGENT);
                b1 = __hip_atomic_load(sp + 1, __ATOMIC_RELAXED,
                                       __HIP_MEMORY_SCOPE_AGENT);
                if (TAGOK(a0) & TAGOK(a1)) { l0 = a0; l1 = a1; break; }
                a0 = __hip_atomic_load(sp + 0, __ATOMIC_RELAXED,
                                       __HIP_MEMORY_SCOPE_AGENT);
                a1 = __hip_atomic_load(sp + 1, __ATOMIC_RELAXED,
                                       __HIP_MEMORY_SCOPE_AGENT);
                if (TAGOK(b0) & TAGOK(b1)) { l0 = b0; l1 = b1; break; }
                if ((guard += 2) > (1 << 20)) { l0 = a0; l1 = a1; break; }
            }

            double cd = __longlong_as_double(
                (long long)(((l0 >> 32) << 32) | (l1 >> 32)));
            int    ci = (int)(l0 & 0xFFFFull);

            // ---- 64-lane butterfly over (cd, ci) for the batch winner ----
#pragma unroll
            for (int m = 1; m < 64; m <<= 1) {
                const double od = __shfl_xor(cd, m, 64);
                const int    oi = __shfl_xor(ci, m, 64);
                const bool t = (od > cd) || (od == cd && oi < ci);
                cd = t ? od : cd; ci = t ? oi : ci;
            }

            if (lane == 0) {
                // LDS mailbox: one atomic b64 write {idx|tag}
                __hip_atomic_store(&s_flag[par],
                                   ((unsigned long long)(unsigned)ci << 32)
                                 | (unsigned long long)tag,
                                   __ATOMIC_RELAXED,
                                   __HIP_MEMORY_SCOPE_WORKGROUP);
                if (blk == 0) out[g * NPOINTS + it + 1] = ci;
            }
            wi = ci;
        } else {
            // ---- waves 1..3: spin on the LDS mailbox (intra-CU) ----
            unsigned long long fv;
            int guard = 0;
            do {
                fv = __hip_atomic_load(&s_flag[par], __ATOMIC_RELAXED,
                                       __HIP_MEMORY_SCOPE_WORKGROUP);
            } while (((unsigned)fv != tag) && ++guard < (1 << 20));
            wi = (int)(fv >> 32);
        }

        // ---- winner coords: uniform read-only fetch, per wave in parallel
        const float* pw = P + (size_t)(unsigned)wi * 3;
        qx = (double)pw[0]; qy = (double)pw[1]; qz = (double)pw[2];
    }
}

extern "C" void kernel_launch(void* const* d_in, const int* in_sizes, int n_in,
                              void* d_out, int out_size, void* d_ws, size_t ws_size,
                              hipStream_t stream) {
    (void)in_sizes; (void)n_in; (void)out_size; (void)ws_size;
    // d_in[0] = npoints (scalar, fixed 2048 per setup), d_in[1] = t_in
    const float* t_in = (const float*)d_in[1];
    int* out = (int*)d_out;
    unsigned long long* slots = (unsigned long long*)d_ws;  // 128 KB used

    dim3 grid(NBATCH * KBLK);
    dim3 block(THREADS);
    void* args[] = { (void*)&t_in, (void*)&out, (void*)&slots };
    hipLaunchCooperativeKernel((const void*)fps_kernel, grid, block, args, 0, stream);
}